// Round 1
// 110.799 us; speedup vs baseline: 1.1744x; 1.1744x over previous
//
#include <hip/hip_runtime.h>
#include <hip/hip_fp16.h>

// MCLoss: mean |lap(gt) - lap(pr)| == mean |lap(gt - pr)|  (laplacian linear).
// B=16, N=100000, M=9, nb[:,0]==i.
//
// k1: tiled (LDS) transpose+diff: d[i][b] = half4(gt[b,i]-pr[b,i], pad)
//     layout (N+1, 16) of 8B half4 -> gather row = 128B, 2 full cache lines.
//     Row N zeroed (absorbs idx==N). float4 phase-1 loads, TI=128.
//     Also zeroes *out (k2 accumulates pre-scaled into it; no k3 kernel).
// k2: per thread: FOUR i's x one b; 36+ independent dwordx2 gathers in flight
//     (latency-bound kernel -> maximize wave-level MLP). 16 lanes sharing i
//     gather a 128B contiguous row.

#define NT 256
#define TI 128  // i's per k1 block

union H4 {
  uint2 u;
  __half2 h[2];  // h[0]=(x,y) h[1]=(z,pad)
};

__global__ __launch_bounds__(NT) void k1_diff_pack(
    const float* __restrict__ gt, const float* __restrict__ pr,
    uint2* __restrict__ d, float* __restrict__ out, int N) {
  __shared__ float sm[16][3 * TI + 1];   // +1 pad: phase-2 stride 385 (bank-free)
  const int t = threadIdx.x;
  const int i0 = blockIdx.x * TI;
  const int ni = min(TI, N - i0);        // valid i count in this tile
  const int nf = 3 * ni;

  // Phase 1: coalesced float4 reads. 16 segments x 384 consecutive floats.
  // (b*N + i0)*3 = b*300000 + 384*blockIdx -> float4 aligned.
#pragma unroll
  for (int k = 0; k < (16 * 3 * TI) / (4 * NT); k++) {   // 6 iters
    int f4 = t + k * NT;
    int b = f4 / (3 * TI / 4);            // /96
    int o4 = f4 - b * (3 * TI / 4);
    int off = o4 * 4;
    size_t gbase = ((size_t)b * N + i0) * 3;
    if (off + 4 <= nf) {
      float4 gv = *(const float4*)(gt + gbase + off);
      float4 pv = *(const float4*)(pr + gbase + off);
      sm[b][off + 0] = gv.x - pv.x;
      sm[b][off + 1] = gv.y - pv.y;
      sm[b][off + 2] = gv.z - pv.z;
      sm[b][off + 3] = gv.w - pv.w;
    } else {
#pragma unroll
      for (int c = 0; c < 4; c++) {
        int o = off + c;
        float v = 0.0f;
        if (o < nf) v = gt[gbase + o] - pr[gbase + o];
        sm[b][o] = v;                     // o <= 383 always
      }
    }
  }
  __syncthreads();

  // Phase 2: coalesced 8B writes in transposed (i,b) order.
#pragma unroll
  for (int k = 0; k < (16 * TI) / NT; k++) {             // 8 iters
    int el = t + k * NT;
    int il = el >> 4;
    int b = el & 15;
    if (il < ni) {
      float x = sm[b][il * 3 + 0];
      float y = sm[b][il * 3 + 1];
      float z = sm[b][il * 3 + 2];
      H4 o;
      o.h[0] = __floats2half2_rn(x, y);
      o.h[1] = __floats2half2_rn(z, 0.0f);
      d[(size_t)(i0 + il) * 16 + b] = o.u;
    }
  }

  if (blockIdx.x == 0) {
    if (t < 16) { uint2 z; z.x = 0u; z.y = 0u; d[(size_t)N * 16 + t] = z; }
    if (t == 16) *out = 0.0f;
  }
}

__device__ __forceinline__ void unpack(uint2 v, float& x, float& y, float& z) {
  H4 c; c.u = v;
  float2 xy = __half22float2(c.h[0]);
  x = xy.x; y = xy.y;
  z = __half2float(__low2half(c.h[1]));
}

__global__ __launch_bounds__(NT) void k2_lap_loss(
    const uint2* __restrict__ dp, const int* __restrict__ nb,
    const float* __restrict__ nn, float* __restrict__ out, int N,
    float scale) {
  const int f = blockIdx.x * NT + threadIdx.x;
  const int g = f >> 4;          // i-quad index
  const int b = f & 15;
  const int i0 = g * 4;
  float s = 0.0f;

  if (i0 + 3 < N) {
    // --- issue ALL loads up front (4 centers + 32 neighbor gathers + nb + nn) ---
    int idx[4][8];
#pragma unroll
    for (int q = 0; q < 4; q++) {
      const int* r = nb + (size_t)(i0 + q) * 9 + 1;
#pragma unroll
      for (int j = 0; j < 8; j++) idx[q][j] = r[j];
    }
    float w[4];
#pragma unroll
    for (int q = 0; q < 4; q++) w[q] = nn[i0 + q];
    uint2 c[4];
#pragma unroll
    for (int q = 0; q < 4; q++) c[q] = dp[(size_t)(i0 + q) * 16 + b];
    uint2 v[4][8];
#pragma unroll
    for (int q = 0; q < 4; q++) {
#pragma unroll
      for (int j = 0; j < 8; j++) v[q][j] = dp[(size_t)idx[q][j] * 16 + b];
    }

#pragma unroll
    for (int q = 0; q < 4; q++) {
      float ax, ay, az;
      unpack(c[q], ax, ay, az);
      ax *= w[q]; ay *= w[q]; az *= w[q];
#pragma unroll
      for (int j = 0; j < 8; j++) {
        float x, y, z; unpack(v[q][j], x, y, z);
        ax -= x; ay -= y; az -= z;
      }
      s += fabsf(ax) + fabsf(ay) + fabsf(az);
    }
  } else if (i0 < N) {
    // tail quad (not hit for N divisible by 4; kept generic)
    for (int q = 0; q < 4; q++) {
      int i = i0 + q;
      if (i >= N) break;
      const int* r = nb + (size_t)i * 9 + 1;
      int ia[8];
#pragma unroll
      for (int j = 0; j < 8; j++) ia[j] = r[j];
      float w = nn[i];
      uint2 cc = dp[(size_t)i * 16 + b];
      uint2 vv[8];
#pragma unroll
      for (int j = 0; j < 8; j++) vv[j] = dp[(size_t)ia[j] * 16 + b];
      float ax, ay, az;
      unpack(cc, ax, ay, az);
      ax *= w; ay *= w; az *= w;
#pragma unroll
      for (int j = 0; j < 8; j++) {
        float x, y, z; unpack(vv[j], x, y, z);
        ax -= x; ay -= y; az -= z;
      }
      s += fabsf(ax) + fabsf(ay) + fabsf(az);
    }
  }

  // wave (64-lane) reduction, then block, then one pre-scaled atomic to out
#pragma unroll
  for (int off = 32; off > 0; off >>= 1) s += __shfl_down(s, off);
  __shared__ float sm[NT / 64];
  int lane = threadIdx.x & 63, wv = threadIdx.x >> 6;
  if (lane == 0) sm[wv] = s;
  __syncthreads();
  if (threadIdx.x == 0) {
    float tt = 0.0f;
#pragma unroll
    for (int k = 0; k < NT / 64; k++) tt += sm[k];
    atomicAdd(out, tt * scale);
  }
}

// ---------- fallback path (tiny ws or K != 8): direct fp32 gather ----------
__global__ void k0_zero(float* __restrict__ out) {
  if (threadIdx.x == 0) *out = 0.0f;
}

__global__ __launch_bounds__(NT) void k2_direct(
    const float* __restrict__ gt, const float* __restrict__ pr,
    const int* __restrict__ nb, const float* __restrict__ nn,
    float* __restrict__ out, int N, int K, float scale) {
  int u = blockIdx.x * NT + threadIdx.x;
  float s = 0.0f;
  if (u < 16 * N) {
    int b = u / N;
    int i = u - b * N;
    size_t cidx = ((size_t)b * N + i) * 3;
    float w = nn[i];
    float ax = (gt[cidx] - pr[cidx]) * w;
    float ay = (gt[cidx + 1] - pr[cidx + 1]) * w;
    float az = (gt[cidx + 2] - pr[cidx + 2]) * w;
    const int* row = nb + (size_t)i * (K + 1) + 1;
    for (int j = 0; j < K; j++) {
      int idx = row[j];
      if (idx < N) {
        size_t p = ((size_t)b * N + idx) * 3;
        ax -= (gt[p] - pr[p]);
        ay -= (gt[p + 1] - pr[p + 1]);
        az -= (gt[p + 2] - pr[p + 2]);
      }
    }
    s = fabsf(ax) + fabsf(ay) + fabsf(az);
  }
#pragma unroll
  for (int off = 32; off > 0; off >>= 1) s += __shfl_down(s, off);
  __shared__ float sm[NT / 64];
  int lane = threadIdx.x & 63, wv = threadIdx.x >> 6;
  if (lane == 0) sm[wv] = s;
  __syncthreads();
  if (threadIdx.x == 0) {
    float tt = 0.0f;
#pragma unroll
    for (int k = 0; k < NT / 64; k++) tt += sm[k];
    atomicAdd(out, tt * scale);
  }
}

extern "C" void kernel_launch(void* const* d_in, const int* in_sizes, int n_in,
                              void* d_out, int out_size, void* d_ws, size_t ws_size,
                              hipStream_t stream) {
  const float* gt = (const float*)d_in[0];
  const float* pr = (const float*)d_in[1];
  const int*   nb = (const int*)d_in[2];
  const float* nn = (const float*)d_in[3];
  int N = in_sizes[3];           // 100000
  int M = in_sizes[2] / N;       // 9
  int K = M - 1;                 // 8

  float scale = 1.0f / (16.0f * (float)N * 3.0f);
  size_t need = (size_t)(N + 1) * 16 * sizeof(uint2);

  if (K == 8 && ws_size >= need) {
    uint2* d = (uint2*)d_ws;

    int b1 = (N + TI - 1) / TI;
    k1_diff_pack<<<b1, NT, 0, stream>>>(gt, pr, d, (float*)d_out, N);

    int groups = (N + 3) / 4;
    int b2 = ((size_t)groups * 16 + NT - 1) / NT;
    k2_lap_loss<<<b2, NT, 0, stream>>>(d, nb, nn, (float*)d_out, N, scale);
  } else {
    k0_zero<<<1, 64, 0, stream>>>((float*)d_out);
    int b2 = (16 * N + NT - 1) / NT;
    k2_direct<<<b2, NT, 0, stream>>>(gt, pr, nb, nn, (float*)d_out, N, K, scale);
  }
}